// Round 2
// baseline (304.294 us; speedup 1.0000x reference)
//
#include <hip/hip_runtime.h>

// Bilinear warp (grid_sample align_corners=True, padding_mode='border').
// src: [B=8, C=16, H=512, W=512] f32, flow: [B, 2, H, W] f32 -> out [B,C,H,W] f32.
// Normalize/unnormalize in the reference cancels exactly: py = clip(h+flow0, 0, H-1).
//
// R1: 2 pixels/thread (dwordx2 flow loads + stores), gathers batched
// 4 channels x 4 taps x 2 px = 32 loads in flight per batch to hide latency.

#define BB 8
#define CC 16
#define HH 512
#define WW 512

__global__ __launch_bounds__(256) void warp_kernel(
    const float* __restrict__ src,
    const float* __restrict__ flow,
    float* __restrict__ out)
{
    const int HW = HH * WW;
    int t = blockIdx.x * blockDim.x + threadIdx.x;
    int pix0 = t * 2;                       // this thread: pixels pix0, pix0+1
    if (pix0 >= BB * HW) return;

    int b   = pix0 >> 18;                   // / (512*512)
    int hw0 = pix0 & (HW - 1);              // even; hw0 and hw0+1 share b
    int h   = hw0 >> 9;
    int w0  = hw0 & (WW - 1);               // w0 and w0+1 in same row (hw0 even)

    const float* fb = flow + (size_t)b * 2 * HW;
    float2 fy = *(const float2*)(fb + hw0);        // y displacement, both px
    float2 fx = *(const float2*)(fb + HW + hw0);   // x displacement, both px

    int   off[2][4];
    float wt[2][4];

    #pragma unroll
    for (int k = 0; k < 2; ++k) {
        float f0 = (k == 0) ? fy.x : fy.y;
        float f1 = (k == 0) ? fx.x : fx.y;
        float py = fminf(fmaxf((float)h + f0, 0.0f), (float)(HH - 1));
        float px = fminf(fmaxf((float)(w0 + k) + f1, 0.0f), (float)(WW - 1));
        float y0f = floorf(py);
        float x0f = floorf(px);
        float wy = py - y0f;
        float wx = px - x0f;
        int y0 = (int)y0f;
        int x0 = (int)x0f;
        int y1 = min(y0 + 1, HH - 1);
        int x1 = min(x0 + 1, WW - 1);
        off[k][0] = y0 * WW + x0;
        off[k][1] = y0 * WW + x1;
        off[k][2] = y1 * WW + x0;
        off[k][3] = y1 * WW + x1;
        wt[k][0] = (1.0f - wy) * (1.0f - wx);
        wt[k][1] = (1.0f - wy) * wx;
        wt[k][2] = wy * (1.0f - wx);
        wt[k][3] = wy * wx;
    }

    const float* sb = src + (size_t)b * CC * HW;
    float*       ob = out + (size_t)b * CC * HW;

    #pragma unroll
    for (int cb = 0; cb < CC; cb += 4) {
        // Batch all 32 loads (4 ch x 4 taps x 2 px) before any use.
        float v[4][4][2];   // [ch][tap][pix]
        #pragma unroll
        for (int j = 0; j < 4; ++j) {
            const float* sc = sb + (size_t)(cb + j) * HW;
            #pragma unroll
            for (int tap = 0; tap < 4; ++tap) {
                v[j][tap][0] = sc[off[0][tap]];
                v[j][tap][1] = sc[off[1][tap]];
            }
        }
        #pragma unroll
        for (int j = 0; j < 4; ++j) {
            float2 r;
            r.x = v[j][0][0] * wt[0][0] + v[j][1][0] * wt[0][1]
                + v[j][2][0] * wt[0][2] + v[j][3][0] * wt[0][3];
            r.y = v[j][0][1] * wt[1][0] + v[j][1][1] * wt[1][1]
                + v[j][2][1] * wt[1][2] + v[j][3][1] * wt[1][3];
            *(float2*)(ob + (size_t)(cb + j) * HW + hw0) = r;
        }
    }
}

extern "C" void kernel_launch(void* const* d_in, const int* in_sizes, int n_in,
                              void* d_out, int out_size, void* d_ws, size_t ws_size,
                              hipStream_t stream) {
    const float* src  = (const float*)d_in[0];
    const float* flow = (const float*)d_in[1];
    float* out = (float*)d_out;

    const int n_thr = BB * HH * WW / 2;      // 1,048,576 threads (2 px each)
    dim3 block(256);
    dim3 grid((n_thr + 255) / 256);          // 4096 blocks
    warp_kernel<<<grid, block, 0, stream>>>(src, flow, out);
}